// Round 1
// baseline (3470.778 us; speedup 1.0000x reference)
//
#include <hip/hip_runtime.h>

#define V 512
#define L 13
#define C 32
#define NB 64
#define S 3
#define LP 16   // padded L for float4 reads
#define CO 32
#define KT 3
#define T 11    // L - KT + 1
#define VT 8    // v per conv block
#define CT 16   // ci tile in conv

// workspace layout: hb[n_local][6][C][V][L] fp32
// block order (concat axis): g0=x, g1=A1x, g2=A1^2x, g3=A2x, g4=A2^2x, g5=A3x, g6=A3^2x
// hb stores g1..g6 at block index bi=g-1; hop1 writes bi=2s, hop2 reads bi=2s writes bi=2s+1.

__global__ __launch_bounds__(256)
void nconv_kernel(const float* __restrict__ x, const float* __restrict__ A,
                  float* __restrict__ hb, int nbase, int mode) {
  const int c  = blockIdx.x;
  const int ny = blockIdx.y;
  const int s  = blockIdx.z;
  const int tid = threadIdx.x;

  const float* Xp;
  float* Yp;
  if (mode == 0) {
    Xp = x  + (((size_t)(nbase + ny) * C + c) * V) * L;
    Yp = hb + ((((size_t)ny * 6 + 2 * s) * C + c) * V) * L;
  } else {
    Xp = hb + ((((size_t)ny * 6 + 2 * s) * C + c) * V) * L;
    Yp = hb + ((((size_t)ny * 6 + 2 * s + 1) * C + c) * V) * L;
  }
  const float* Ap = A + (size_t)s * V * V;

  __shared__ float Xs[V * LP];   // 32 KB
  for (int idx = tid; idx < V * L; idx += 256) {
    int v = idx / L;
    int l = idx - v * L;
    Xs[v * LP + l] = Xp[idx];
  }
  __syncthreads();

  float acc0[13], acc1[13];
  #pragma unroll
  for (int i = 0; i < 13; ++i) { acc0[i] = 0.f; acc1[i] = 0.f; }

  // thread owns output rows w0=tid, w1=tid+256; A[w,v] row-major
  const float* Ar0 = Ap + (size_t)tid * V;
  const float* Ar1 = Ap + ((size_t)tid + 256) * V;

  for (int v = 0; v < V; v += 4) {
    float4 a0 = *(const float4*)(Ar0 + v);
    float4 a1 = *(const float4*)(Ar1 + v);
    #pragma unroll
    for (int j = 0; j < 4; ++j) {
      float aa0 = (j == 0) ? a0.x : (j == 1) ? a0.y : (j == 2) ? a0.z : a0.w;
      float aa1 = (j == 0) ? a1.x : (j == 1) ? a1.y : (j == 2) ? a1.z : a1.w;
      const float* xr = Xs + (v + j) * LP;
      #pragma unroll
      for (int q = 0; q < 3; ++q) {
        float4 xv = *(const float4*)(xr + q * 4);
        acc0[q*4+0] += aa0 * xv.x; acc0[q*4+1] += aa0 * xv.y;
        acc0[q*4+2] += aa0 * xv.z; acc0[q*4+3] += aa0 * xv.w;
        acc1[q*4+0] += aa1 * xv.x; acc1[q*4+1] += aa1 * xv.y;
        acc1[q*4+2] += aa1 * xv.z; acc1[q*4+3] += aa1 * xv.w;
      }
      float xl = xr[12];
      acc0[12] += aa0 * xl;
      acc1[12] += aa1 * xl;
    }
  }

  float* y0 = Yp + (size_t)tid * L;
  float* y1 = Yp + ((size_t)tid + 256) * L;
  #pragma unroll
  for (int l = 0; l < 13; ++l) y0[l] = acc0[l];
  #pragma unroll
  for (int l = 0; l < 13; ++l) y1[l] = acc1[l];
}

__global__ __launch_bounds__(256)
void conv_kernel(const float* __restrict__ x, const float* __restrict__ hb,
                 const float* __restrict__ W, const float* __restrict__ b,
                 float* __restrict__ y, int nbase) {
  const int v0  = blockIdx.x * VT;
  const int ny  = blockIdx.y;
  const int n   = nbase + ny;
  const int tid = threadIdx.x;
  const int o   = tid >> 3;   // 0..31
  const int vl  = tid & 7;    // 0..7

  __shared__ float Ws[CT * CO * KT];   // [ci][o][kt], 6 KB
  __shared__ float Hs[CT * VT * LP];   // [ci][v][l], l-groups XOR-swizzled by (v&3); 8 KB

  float acc[T];
  #pragma unroll
  for (int t = 0; t < T; ++t) acc[t] = 0.f;

  const int C_cat = (2 * S + 1) * C;   // 224

  for (int ct = 0; ct < C_cat / CT; ++ct) {
    // stage W tile: Ws[ci*96 + o*3 + kt] = W[o, ct*16+ci, 0, kt]
    for (int idx = tid; idx < CT * CO * KT; idx += 256) {
      int ci = idx / (CO * KT);
      int r  = idx - ci * (CO * KT);      // r = o*3 + kt
      int oo = r / KT;
      int kt = r - oo * KT;
      Ws[idx] = W[(size_t)oo * (C_cat * KT) + (size_t)(ct * CT + ci) * KT + kt];
    }
    // stage H tile (group 0 comes from x, groups 1..6 from hb)
    for (int idx = tid; idx < CT * VT * L; idx += 256) {
      int ci = idx / (VT * L);
      int r  = idx - ci * (VT * L);
      int v  = r / L;
      int l  = r - v * L;
      int gci = ct * CT + ci;
      const float* src;
      if (gci < C) {
        src = x + (((size_t)n * C + gci) * V + v0 + v) * L + l;
      } else {
        int bi = (gci - C) >> 5;
        int cc = (gci - C) & 31;
        src = hb + ((((size_t)ny * 6 + bi) * C + cc) * V + v0 + v) * L + l;
      }
      int q = l >> 2, j = l & 3;
      Hs[(ci * VT + v) * LP + ((q ^ (v & 3)) << 2) + j] = *src;
    }
    __syncthreads();

    #pragma unroll
    for (int ci = 0; ci < CT; ++ci) {
      const float* wp = Ws + ci * (CO * KT) + o * KT;
      float w0 = wp[0], w1 = wp[1], w2 = wp[2];
      const float* hr = Hs + (ci * VT + vl) * LP;
      #pragma unroll
      for (int q = 0; q < 4; ++q) {
        float4 hv = *(const float4*)(hr + ((q ^ (vl & 3)) << 2));
        #pragma unroll
        for (int j = 0; j < 4; ++j) {
          const int l = q * 4 + j;
          float h = (j == 0) ? hv.x : (j == 1) ? hv.y : (j == 2) ? hv.z : hv.w;
          if (l < T)                acc[l]     += w0 * h;  // t = l
          if (l >= 1 && l - 1 < T)  acc[l - 1] += w1 * h;  // t = l-1
          if (l >= 2 && l - 2 < T)  acc[l - 2] += w2 * h;  // t = l-2
        }
      }
    }
    __syncthreads();
  }

  float bias = b[o];
  float* yp = y + (((size_t)n * CO + o) * V + v0 + vl) * T;
  #pragma unroll
  for (int t = 0; t < T; ++t) yp[t] = acc[t] + bias;
}

extern "C" void kernel_launch(void* const* d_in, const int* in_sizes, int n_in,
                              void* d_out, int out_size, void* d_ws, size_t ws_size,
                              hipStream_t stream) {
  const float* x = (const float*)d_in[0];
  const float* A = (const float*)d_in[1];
  const float* W = (const float*)d_in[2];
  const float* b = (const float*)d_in[3];
  float* y  = (float*)d_out;
  float* hb = (float*)d_ws;

  const size_t per_n = 6ull * C * V * L * sizeof(float);  // 5.11 MB
  int nc = (int)(ws_size / per_n);
  if (nc < 1) nc = 1;
  if (nc > NB) nc = NB;

  for (int n0 = 0; n0 < NB; n0 += nc) {
    int nn = (NB - n0 < nc) ? (NB - n0) : nc;
    hipLaunchKernelGGL(nconv_kernel, dim3(C, nn, S), dim3(256), 0, stream,
                       x, A, hb, n0, 0);
    hipLaunchKernelGGL(nconv_kernel, dim3(C, nn, S), dim3(256), 0, stream,
                       x, A, hb, n0, 1);
    hipLaunchKernelGGL(conv_kernel, dim3(V / VT, nn), dim3(256), 0, stream,
                       x, hb, W, b, y, n0);
  }
}

// Round 2
// 439.203 us; speedup vs baseline: 7.9024x; 7.9024x over previous
//
#include <hip/hip_runtime.h>

typedef __attribute__((ext_vector_type(4))) float f32x4;
typedef __attribute__((ext_vector_type(2))) float f32x2;
typedef __attribute__((ext_vector_type(8))) __bf16 bf16x8;
typedef __attribute__((ext_vector_type(4))) __bf16 bf16x4;

#define SXE (26624 * 512)   // elements of one [b][v] matrix (b = n*32c*13l)

// ---------------- prep: x[n][c][v][l] f32 -> Xv[(n*32+c)*13+l][v] bf16 ----------------
__global__ __launch_bounds__(256)
void prep_x(const float* __restrict__ x, __bf16* __restrict__ Xv) {
  const int c = blockIdx.x, n = blockIdx.y, tid = threadIdx.x;
  __shared__ float Xs[512 * 13];
  const float* src = x + ((size_t)(n * 32 + c)) * 512 * 13;
  for (int i = tid; i < 512 * 13; i += 256) Xs[i] = src[i];
  __syncthreads();
  __bf16* dst = Xv + ((size_t)(n * 32 + c)) * 13 * 512;
  for (int i = tid; i < 512 * 13; i += 256) {
    const int l = i >> 9, v = i & 511;
    dst[(size_t)l * 512 + v] = (__bf16)Xs[v * 13 + l];  // stride-13 LDS read: 13 coprime 32, conflict-free
  }
}

__global__ __launch_bounds__(256)
void cast_A(const float* __restrict__ A, __bf16* __restrict__ Ab) {
  const int i = blockIdx.x * 256 + threadIdx.x;  // 768*256 = 196608 = 3*512*512/4
  const float4 f = ((const float4*)A)[i];
  bf16x4 o;
  o[0] = (__bf16)f.x; o[1] = (__bf16)f.y; o[2] = (__bf16)f.z; o[3] = (__bf16)f.w;
  ((bf16x4*)Ab)[i] = o;
}

// ---------------- diffusion GEMM: D[b][w] = sum_v A_s[w][v] * SRC[b][v] ----------------
// m97 structure: 128x128 tile, BK=64, global_load_lds w16, XOR-swizzled LDS (chunk ^= row&7).
__global__ __launch_bounds__(256)
void gemm_bf16(const __bf16* __restrict__ Ab, const __bf16* __restrict__ SRC,
               __bf16* __restrict__ DSTB, int srcStride, int dstStride) {
  const int tid = threadIdx.x;
  const int lane = tid & 63, wave = tid >> 6;
  const int bx = blockIdx.x, by = blockIdx.y, s = blockIdx.z;

  const __bf16* Amat = Ab + (size_t)s * 512 * 512;
  const __bf16* B = SRC + (size_t)s * srcStride;
  __bf16* D = DSTB + (size_t)s * dstStride;

  const int W0 = by * 128, B0 = bx * 128;
  const int wm = wave >> 1, wn = wave & 1;

  __shared__ __bf16 As[128 * 64];
  __shared__ __bf16 Bs[128 * 64];

  f32x4 acc[4][4];
  #pragma unroll
  for (int m = 0; m < 4; ++m)
    #pragma unroll
    for (int n = 0; n < 4; ++n) acc[m][n] = {0.f, 0.f, 0.f, 0.f};

  const int srow = lane >> 3;   // 0..7 within slot
  const int spos = lane & 7;    // lds 16B-chunk position within row

  for (int kt = 0; kt < 8; ++kt) {
    const int k0 = kt * 64;
    #pragma unroll
    for (int i = 0; i < 4; ++i) {
      const int slot = i * 4 + wave;          // 16 slots x 1KB = 16KB tile
      const int r = slot * 8 + srow;          // tile row 0..127
      const int gc = spos ^ (r & 7);          // inverse-swizzled global chunk
      const __bf16* ga = Amat + (size_t)(W0 + r) * 512 + k0 + gc * 8;
      const __bf16* gb = B    + (size_t)(B0 + r) * 512 + k0 + gc * 8;
      char* la = (char*)As + slot * 1024 + lane * 16;  // lane0 value = wave-uniform base
      char* lb = (char*)Bs + slot * 1024 + lane * 16;
      __builtin_amdgcn_global_load_lds((const __attribute__((address_space(1))) unsigned int*)ga,
                                       (__attribute__((address_space(3))) unsigned int*)la, 16, 0, 0);
      __builtin_amdgcn_global_load_lds((const __attribute__((address_space(1))) unsigned int*)gb,
                                       (__attribute__((address_space(3))) unsigned int*)lb, 16, 0, 0);
    }
    __syncthreads();
    #pragma unroll
    for (int ks = 0; ks < 2; ++ks) {
      bf16x8 af[4], bfv[4];
      const int ch = ks * 4 + (lane >> 4);  // k-chunk 0..7 (contiguous-8 per lane; same bijection both operands)
      #pragma unroll
      for (int m = 0; m < 4; ++m) {
        const int r = wm * 64 + m * 16 + (lane & 15);
        af[m] = *(const bf16x8*)((const char*)As + r * 128 + ((ch ^ (r & 7)) << 4));
      }
      #pragma unroll
      for (int n = 0; n < 4; ++n) {
        const int r = wn * 64 + n * 16 + (lane & 15);
        bfv[n] = *(const bf16x8*)((const char*)Bs + r * 128 + ((ch ^ (r & 7)) << 4));
      }
      #pragma unroll
      for (int m = 0; m < 4; ++m)
        #pragma unroll
        for (int n = 0; n < 4; ++n)
          acc[m][n] = __builtin_amdgcn_mfma_f32_16x16x32_bf16(af[m], bfv[n], acc[m][n], 0, 0, 0);
    }
    __syncthreads();
  }

  // C/D: col=lane&15 (-> b), row=(lane>>4)*4+reg (-> w). Store to D[b][w]: 4 consecutive w = 8B.
  #pragma unroll
  for (int m = 0; m < 4; ++m) {
    const int w = W0 + wm * 64 + m * 16 + ((lane >> 4) << 2);
    #pragma unroll
    for (int n = 0; n < 4; ++n) {
      const int b = B0 + wn * 64 + n * 16 + (lane & 15);
      bf16x4 o4;
      o4[0] = (__bf16)acc[m][n][0];
      o4[1] = (__bf16)acc[m][n][1];
      o4[2] = (__bf16)acc[m][n][2];
      o4[3] = (__bf16)acc[m][n][3];
      *(bf16x4*)(D + (size_t)b * 512 + w) = o4;
    }
  }
}

// ---------------- temporal conv: y[n][o][v][t] = sum_{cc,kt} W[o][cc][kt] h[n][cc][v][t+kt] + b[o] ----------------
__global__ __launch_bounds__(256)
void conv_kernel(const __bf16* __restrict__ Xv, const __bf16* __restrict__ Y1,
                 const __bf16* __restrict__ Y2, const float* __restrict__ W,
                 const float* __restrict__ bias, float* __restrict__ y) {
  const int vt = blockIdx.x;   // 32 tiles of 16 v
  const int n  = blockIdx.y;
  const int v0 = vt * 16;
  const int tid = threadIdx.x;
  const int o  = tid & 31;
  const int vh = tid >> 5;     // 0..7, v-pair index

  __shared__ float  Hs[32 * 13 * 16];   // [c][l][16v] f32, 26.6 KB
  __shared__ __bf16 Ws[128 * 32 * 4];   // [ccLocal][o][4kt] bf16, 32 KB

  f32x2 acc[11];
  #pragma unroll
  for (int t = 0; t < 11; ++t) acc[t] = {0.f, 0.f};

  const __bf16* gsrc[7];
  gsrc[0] = Xv;
  gsrc[1] = Y1;                     gsrc[2] = Y2;
  gsrc[3] = Y1 + (size_t)SXE;       gsrc[4] = Y2 + (size_t)SXE;
  gsrc[5] = Y1 + 2 * (size_t)SXE;   gsrc[6] = Y2 + 2 * (size_t)SXE;

  for (int ph = 0; ph < 2; ++ph) {
    const int ccbase = ph * 128;
    const int ncc = ph ? 96 : 128;
    __syncthreads();
    for (int idx = tid; idx < ncc * 32; idx += 256) {
      const int ccL = idx >> 5, oo = idx & 31;
      const float* wp = W + ((size_t)oo * 224 + ccbase + ccL) * 3;
      __bf16* d = Ws + (size_t)idx * 4;
      d[0] = (__bf16)wp[0]; d[1] = (__bf16)wp[1]; d[2] = (__bf16)wp[2]; d[3] = (__bf16)0.f;
    }
    const int ng = ph ? 3 : 4;
    for (int gl = 0; gl < ng; ++gl) {
      const int g = ph * 4 + gl;
      const __bf16* src = gsrc[g] + ((size_t)n * 32) * 13 * 512 + v0;
      __syncthreads();
      for (int t = tid; t < 832; t += 256) {     // 416 rows x 2 halves of 16B
        const int row = t >> 1, half = t & 1;
        bf16x8 val = *(const bf16x8*)(src + (size_t)row * 512 + half * 8);
        float* d = Hs + row * 16 + half * 8;
        #pragma unroll
        for (int j = 0; j < 8; ++j) d[j] = (float)val[j];
      }
      __syncthreads();
      for (int c = 0; c < 32; ++c) {
        const int ccL = gl * 32 + c;
        bf16x4 wq = *(const bf16x4*)(Ws + (size_t)(ccL * 32 + o) * 4);
        const float w0 = (float)wq[0], w1 = (float)wq[1], w2 = (float)wq[2];
        const float* hp = Hs + c * 13 * 16 + vh * 2;
        #pragma unroll
        for (int l = 0; l < 13; ++l) {
          f32x2 h2 = *(const f32x2*)(hp + l * 16);
          if (l < 11)             acc[l]     += w0 * h2;
          if (l >= 1 && l <= 11)  acc[l - 1] += w1 * h2;
          if (l >= 2)             acc[l - 2] += w2 * h2;
        }
      }
    }
  }

  const float bo = bias[o];
  #pragma unroll
  for (int vi = 0; vi < 2; ++vi) {
    const int v = v0 + vh * 2 + vi;
    float* yp = y + (((size_t)n * 32 + o) * 512 + v) * 11;
    #pragma unroll
    for (int t = 0; t < 11; ++t) yp[t] = (vi ? acc[t][1] : acc[t][0]) + bo;
  }
}

extern "C" void kernel_launch(void* const* d_in, const int* in_sizes, int n_in,
                              void* d_out, int out_size, void* d_ws, size_t ws_size,
                              hipStream_t stream) {
  (void)in_sizes; (void)n_in; (void)out_size; (void)ws_size;
  const float* x = (const float*)d_in[0];
  const float* A = (const float*)d_in[1];
  const float* W = (const float*)d_in[2];
  const float* b = (const float*)d_in[3];
  float* y = (float*)d_out;

  char* ws = (char*)d_ws;
  const size_t SXB = (size_t)26624 * 512 * 2;      // 27.26 MB per matrix
  __bf16* Xv = (__bf16*)ws;                        // [26624][512]
  __bf16* Y1 = (__bf16*)(ws + SXB);                // 3 x hop-1 outputs
  __bf16* Y2 = (__bf16*)(ws + 4 * SXB);            // 3 x hop-2 outputs
  __bf16* Ab = (__bf16*)(ws + 7 * SXB);            // bf16 A, 1.57 MB  (total ~192.4 MB < ws)

  prep_x<<<dim3(32, 64), 256, 0, stream>>>(x, Xv);
  cast_A<<<dim3(768), 256, 0, stream>>>(A, Ab);
  gemm_bf16<<<dim3(208, 4, 3), 256, 0, stream>>>(Ab, Xv, Y1, 0, SXE);
  gemm_bf16<<<dim3(208, 4, 3), 256, 0, stream>>>(Ab, Y1, Y2, SXE, SXE);
  conv_kernel<<<dim3(32, 64), 256, 0, stream>>>(Xv, Y1, Y2, W, b, y);
}

// Round 4
// 288.026 us; speedup vs baseline: 12.0502x; 1.5249x over previous
//
#include <hip/hip_runtime.h>

typedef __attribute__((ext_vector_type(4))) float f32x4;
typedef __attribute__((ext_vector_type(8))) __bf16 bf16x8;
typedef __attribute__((ext_vector_type(4))) __bf16 bf16x4;
typedef __attribute__((ext_vector_type(4))) int i32x4;

#define NH 32                    // batch rows per half
#define SXE_H (13312 * 512)      // elems of one [b][v] matrix per half, b=(nLocal,l,c), 13312 = 32*13*32
#define HC_ROWS 212992           // 32 n * 13 l * 512 v
#define HC_PITCH 256             // bf16 slots per Hc row (512 B)

// ---------------- prep: x[n][c][v][l] f32 -> Xv2[(ny*13+l)*32+c][v] bf16  AND  Hc[row][c0..31] ----------------
__global__ __launch_bounds__(256)
void prep_x(const float* __restrict__ x, __bf16* __restrict__ Xv2, __bf16* __restrict__ Hc,
            int nbase) {
  const int vt = blockIdx.x, ny = blockIdx.y, tid = threadIdx.x;
  __shared__ float Xs[32 * 209];   // [c][v*13+l], pitch 209 (odd, spreads banks)
  const float* src = x + ((size_t)(nbase + ny) * 32) * 6656 + vt * 16 * 13;  // 512*13=6656 per c
  for (int i = tid; i < 32 * 208; i += 256) {
    const int c = i / 208, r = i - c * 208;
    Xs[c * 209 + r] = src[(size_t)c * 6656 + r];
  }
  __syncthreads();
  // Hc group-0 chunks: row (ny,l,v), 32 c contiguous (64 B)
  if (tid < 208) {
    const int v = tid & 15, l = tid >> 4;
    bf16x8 o8[4];
    #pragma unroll
    for (int c = 0; c < 32; ++c) o8[c >> 3][c & 7] = (__bf16)Xs[c * 209 + v * 13 + l];
    __bf16* d = Hc + (((size_t)ny * 13 + l) * 512 + vt * 16 + v) * HC_PITCH;
    #pragma unroll
    for (int j = 0; j < 4; ++j) *(bf16x8*)(d + j * 8) = o8[j];
  }
  // Xv2 rows (ny,l,c), 16 v chunk (32 B)
  for (int j = tid; j < 416; j += 256) {
    const int c = j & 31, l = j >> 5;
    bf16x8 o8[2];
    #pragma unroll
    for (int v = 0; v < 16; ++v) o8[v >> 3][v & 7] = (__bf16)Xs[c * 209 + v * 13 + l];
    __bf16* d = Xv2 + (((size_t)ny * 13 + l) * 32 + c) * 512 + vt * 16;
    *(bf16x8*)d = o8[0];
    *(bf16x8*)(d + 8) = o8[1];
  }
}

__global__ __launch_bounds__(256)
void cast_A(const float* __restrict__ A, __bf16* __restrict__ Ab) {
  const int i = blockIdx.x * 256 + threadIdx.x;
  const float4 f = ((const float4*)A)[i];
  bf16x4 o;
  o[0] = (__bf16)f.x; o[1] = (__bf16)f.y; o[2] = (__bf16)f.z; o[3] = (__bf16)f.w;
  ((bf16x4*)Ab)[i] = o;
}

// ---------------- diffusion GEMM: D[b][w] = sum_v SRC[b][v] * A_s[w][v]  (A-op = data rows b) ----------------
__global__ __launch_bounds__(256)
void gemm_bf16(const __bf16* __restrict__ Ab, const __bf16* __restrict__ SRC,
               __bf16* __restrict__ Yb, __bf16* __restrict__ Hc,
               int srcStride, int ccBase, int writeY) {
  const int tid = threadIdx.x;
  const int lane = tid & 63, wave = tid >> 6, q = lane >> 4;
  const int bx = blockIdx.x, by = blockIdx.y, s = blockIdx.z;

  const __bf16* Amat = Ab + (size_t)s * 512 * 512;
  const __bf16* B = SRC + (size_t)s * srcStride;
  __bf16* Y = Yb + (size_t)s * SXE_H;
  const int cc0 = ccBase + s * 64;

  const int W0 = by * 128, B0 = bx * 128;
  const int wm = wave >> 1, wn = wave & 1;

  __shared__ char gsm[32768];                 // As(16K)+Bs(16K); reused as Ls2(32K) in epilogue
  char* As = gsm;
  char* Bs = gsm + 16384;

  f32x4 acc[4][4];
  #pragma unroll
  for (int m = 0; m < 4; ++m)
    #pragma unroll
    for (int n = 0; n < 4; ++n) acc[m][n] = {0.f, 0.f, 0.f, 0.f};

  const int srow = lane >> 3, spos = lane & 7;

  for (int kt = 0; kt < 8; ++kt) {
    const int k0 = kt * 64;
    #pragma unroll
    for (int i = 0; i < 4; ++i) {
      const int slot = i * 4 + wave;
      const int r = slot * 8 + srow;
      const int gc = spos ^ (r & 7);          // inverse-swizzled global source (rule 21)
      const __bf16* ga = Amat + (size_t)(W0 + r) * 512 + k0 + gc * 8;
      const __bf16* gb = B    + (size_t)(B0 + r) * 512 + k0 + gc * 8;
      char* la = As + slot * 1024 + lane * 16;
      char* lb = Bs + slot * 1024 + lane * 16;
      __builtin_amdgcn_global_load_lds((const __attribute__((address_space(1))) unsigned int*)ga,
                                       (__attribute__((address_space(3))) unsigned int*)la, 16, 0, 0);
      __builtin_amdgcn_global_load_lds((const __attribute__((address_space(1))) unsigned int*)gb,
                                       (__attribute__((address_space(3))) unsigned int*)lb, 16, 0, 0);
    }
    __syncthreads();
    #pragma unroll
    for (int ks = 0; ks < 2; ++ks) {
      bf16x8 af[4], df[4];
      const int ch = ks * 4 + q;
      #pragma unroll
      for (int n = 0; n < 4; ++n) {                    // A_s frags (B-operand): rows = w
        const int r = wn * 64 + n * 16 + (lane & 15);
        af[n] = *(const bf16x8*)(As + r * 128 + ((ch ^ (r & 7)) << 4));
      }
      #pragma unroll
      for (int m = 0; m < 4; ++m) {                    // data frags (A-operand): rows = b
        const int r = wm * 64 + m * 16 + (lane & 15);
        df[m] = *(const bf16x8*)(Bs + r * 128 + ((ch ^ (r & 7)) << 4));
      }
      #pragma unroll
      for (int m = 0; m < 4; ++m)
        #pragma unroll
        for (int n = 0; n < 4; ++n)
          acc[m][n] = __builtin_amdgcn_mfma_f32_16x16x32_bf16(df[m], af[n], acc[m][n], 0, 0, 0);
    }
    __syncthreads();
  }

  // D: row=b=(lane>>4)*4+reg (+frag), col=w=lane&15 (+frag)
  if (writeY) {   // Y[b][w]: lanes contiguous in w -> 32B sectors
    #pragma unroll
    for (int m = 0; m < 4; ++m) {
      const int brow = B0 + wm * 64 + m * 16 + q * 4;
      #pragma unroll
      for (int n = 0; n < 4; ++n) {
        const int w = W0 + wn * 64 + n * 16 + (lane & 15);
        #pragma unroll
        for (int r = 0; r < 4; ++r)
          Y[(size_t)(brow + r) * 512 + w] = (__bf16)acc[m][n][r];
      }
    }
  }

  // LDS transpose -> Hc 64B row-chunks. Ls2[nl][w][c], 8B units swizzled: pos = ch ^ ((w&3)<<1)
  __syncthreads();
  #pragma unroll
  for (int m = 0; m < 4; ++m) {
    const int boff = wm * 64 + m * 16 + q * 4;
    const int nl = boff >> 5;
    const int ch = (boff & 31) >> 2;
    #pragma unroll
    for (int n = 0; n < 4; ++n) {
      const int w = wn * 64 + n * 16 + (lane & 15);
      bf16x4 o4;
      o4[0] = (__bf16)acc[m][n][0]; o4[1] = (__bf16)acc[m][n][1];
      o4[2] = (__bf16)acc[m][n][2]; o4[3] = (__bf16)acc[m][n][3];
      *(bf16x4*)(gsm + nl * 8192 + w * 64 + ((ch ^ ((w & 3) << 1)) << 3)) = o4;
    }
  }
  __syncthreads();
  for (int j = tid; j < 512; j += 256) {
    const int nl = j >> 7, w = j & 127;
    const size_t row = ((size_t)(bx * 4 + nl)) * 512 + W0 + w;   // (ny*13+l)*512 + v
    __bf16* gd = Hc + row * HC_PITCH + cc0;
    const char* ls = gsm + nl * 8192 + w * 64;
    #pragma unroll
    for (int j4 = 0; j4 < 4; ++j4)
      ((i32x4*)gd)[j4] = *(const i32x4*)(ls + ((j4 ^ (w & 3)) << 4));
  }
}

// ---------------- temporal conv as MFMA: D[(v,t)][o] = sum_{cc,kt} Hc[(ny,l=t+kt,v)][cc] * W2[o][cc,kt] ----------------
__global__ __launch_bounds__(256)
void conv_kernel(const __bf16* __restrict__ Hc, const float* __restrict__ W,
                 const float* __restrict__ bias, float* __restrict__ y, int nbase) {
  const int vt = blockIdx.x;   // 8 tiles of 64 v
  const int ny = blockIdx.y;
  const int tid = threadIdx.x;
  const int lane = tid & 63, wave = tid >> 6, q = lane >> 4;

  __shared__ char sm[59392];   // Ls: [l(13)][v(64)][32cc] = 53248 B; Ws at +53248 (6144 B); Ds overlays Ls
  char* Ws = sm + 53248;

  f32x4 acc[11][2];
  #pragma unroll
  for (int t = 0; t < 11; ++t) { acc[t][0] = {0,0,0,0}; acc[t][1] = {0,0,0,0}; }

  const int vL = wave * 16 + (lane & 15);    // this lane's A-frag row (v within tile)
  const int swzL = (vL >> 1) & 3;

  for (int ci = 0; ci < 7; ++ci) {
    __syncthreads();
    // stage Hc chunk (cc = ci*32..+31) for all 13 l, 64 v: linear LDS dest, inverse-swizzled global src
    for (int qs = wave; qs < 52; qs += 4) {
      const int l = qs >> 2, vq = qs & 3;
      const int v = vq * 16 + (lane >> 2), chn = lane & 3;
      const int cg = chn ^ ((v >> 1) & 3);
      const __bf16* g = Hc + (((size_t)ny * 13 + l) * 512 + vt * 64 + v) * HC_PITCH + ci * 32 + cg * 8;
      char* ld = sm + l * 4096 + vq * 1024 + lane * 16;
      __builtin_amdgcn_global_load_lds((const __attribute__((address_space(1))) unsigned int*)g,
                                       (__attribute__((address_space(3))) unsigned int*)ld, 16, 0, 0);
    }
    // stage W2 chunk fragments: Ws[f=kt*2+of][lane][8] bf16
    for (int i8 = tid; i8 < 768; i8 += 256) {
      const int f = i8 >> 7, r = i8 & 127, lw = r >> 1, half = r & 1;
      const int kt = f >> 1, of = f & 1;
      const int o = of * 16 + (lw & 15);
      const int cc = ci * 32 + (lw >> 4) * 8 + half * 4;
      bf16x4 o4;
      #pragma unroll
      for (int jj = 0; jj < 4; ++jj)
        o4[jj] = (__bf16)W[((size_t)o * 224 + cc + jj) * 3 + kt];
      *(bf16x4*)(Ws + i8 * 8) = o4;
    }
    __syncthreads();

    bf16x8 hl[13];
    #pragma unroll
    for (int l = 0; l < 13; ++l)
      hl[l] = *(const bf16x8*)(sm + l * 4096 + vL * 64 + ((q ^ swzL) << 4));
    bf16x8 wf[6];
    #pragma unroll
    for (int f = 0; f < 6; ++f)
      wf[f] = *(const bf16x8*)(Ws + (f * 64 + lane) * 16);

    #pragma unroll
    for (int kt = 0; kt < 3; ++kt)
      #pragma unroll
      for (int of = 0; of < 2; ++of)
        #pragma unroll
        for (int t = 0; t < 11; ++t)
          acc[t][of] = __builtin_amdgcn_mfma_f32_16x16x32_bf16(hl[t + kt], wf[kt * 2 + of], acc[t][of], 0, 0, 0);
  }

  // epilogue: two passes of 16 o through Ds[o16][v(64)][t(11)] f32 (pitch 708), then coalesced y stores
  float* Ds = (float*)sm;
  const int o16 = lane & 15;
  for (int p = 0; p < 2; ++p) {
    __syncthreads();
    #pragma unroll
    for (int t = 0; t < 11; ++t) {
      const int vbase = wave * 16 + q * 4;
      #pragma unroll
      for (int r = 0; r < 4; ++r)
        Ds[o16 * 708 + (vbase + r) * 11 + t] = acc[t][p][r];
    }
    __syncthreads();
    for (int i = 0; i < 11; ++i) {
      const int cg = tid + i * 256;           // 16 o * 176 chunks
      const int oo = cg / 176, ch = cg - oo * 176;
      f32x4 v4 = *(const f32x4*)(Ds + oo * 708 + ch * 4);
      const float bo = bias[p * 16 + oo];
      v4[0] += bo; v4[1] += bo; v4[2] += bo; v4[3] += bo;
      float* yp = y + (((size_t)(nbase + ny) * 32 + p * 16 + oo) * 512 + vt * 64) * 11 + ch * 4;
      *(f32x4*)yp = v4;
    }
  }
}

extern "C" void kernel_launch(void* const* d_in, const int* in_sizes, int n_in,
                              void* d_out, int out_size, void* d_ws, size_t ws_size,
                              hipStream_t stream) {
  (void)in_sizes; (void)n_in; (void)out_size; (void)ws_size;
  const float* x = (const float*)d_in[0];
  const float* A = (const float*)d_in[1];
  const float* W = (const float*)d_in[2];
  const float* b = (const float*)d_in[3];
  float* y = (float*)d_out;

  // Per-half workspace (reused for both halves): total ~165.2 MB (< 192.4 MB known-good)
  char* ws = (char*)d_ws;
  const size_t SXB_H = (size_t)SXE_H * 2;              // 13.63 MB
  __bf16* Xv2 = (__bf16*)ws;                           // [13312][512]
  __bf16* Y1  = (__bf16*)(ws + SXB_H);                 // 3 x hop-1 [b][v]
  __bf16* Hc  = (__bf16*)(ws + 4 * SXB_H);             // [212992][256] = 109.1 MB
  __bf16* Ab  = (__bf16*)(ws + 4 * SXB_H + (size_t)HC_ROWS * 512);  // 1.57 MB

  cast_A<<<dim3(768), 256, 0, stream>>>(A, Ab);
  for (int h = 0; h < 2; ++h) {
    const int nbase = h * NH;
    prep_x<<<dim3(32, NH), 256, 0, stream>>>(x, Xv2, Hc, nbase);
    // hop1: B = Xv2 (shared across s), writes Y1 + Hc cc=32+s*64
    gemm_bf16<<<dim3(104, 4, 3), 256, 0, stream>>>(Ab, Xv2, Y1, Hc, 0, 32, 1);
    // hop2: B = Y1 (per s), writes Hc cc=64+s*64
    gemm_bf16<<<dim3(104, 4, 3), 256, 0, stream>>>(Ab, Y1, Y1, Hc, SXE_H, 64, 0);
    conv_kernel<<<dim3(8, NH), 256, 0, stream>>>(Hc, W, b, y, nbase);
  }
}

// Round 7
// 235.617 us; speedup vs baseline: 14.7306x; 1.2224x over previous
//
#include <hip/hip_runtime.h>

typedef __attribute__((ext_vector_type(4))) float f32x4;
typedef __attribute__((ext_vector_type(8))) __bf16 bf16x8;
typedef __attribute__((ext_vector_type(4))) __bf16 bf16x4;
typedef __attribute__((ext_vector_type(4))) int i32x4;

#define SXE (26624 * 512)   // elems of one [b][v] matrix, b=(n,l,c): 64*13*32 rows x 512

// ---------------- prep: x[n][c][v][l] f32 -> Xv2[(n*13+l)*32+c][v] bf16 ----------------
__global__ __launch_bounds__(256)
void prep_x(const float* __restrict__ x, __bf16* __restrict__ Xv2) {
  const int vt = blockIdx.x, n = blockIdx.y, tid = threadIdx.x;
  __shared__ float Xs[32 * 209];   // [c][v*13+l] for 16 v, pitch 209 (odd)
  const float* src = x + ((size_t)n * 32) * 6656 + vt * 16 * 13;
  for (int i = tid; i < 32 * 208; i += 256) {
    const int c = i / 208, r = i - c * 208;
    Xs[c * 209 + r] = src[(size_t)c * 6656 + r];
  }
  __syncthreads();
  for (int j = tid; j < 416; j += 256) {   // (l,c) rows, 16-v chunks
    const int c = j & 31, l = j >> 5;
    bf16x8 o8[2];
    #pragma unroll
    for (int v = 0; v < 16; ++v) o8[v >> 3][v & 7] = (__bf16)Xs[c * 209 + v * 13 + l];
    __bf16* d = Xv2 + (((size_t)n * 13 + l) * 32 + c) * 512 + vt * 16;
    *(bf16x8*)d = o8[0];
    *(bf16x8*)(d + 8) = o8[1];
  }
}

__global__ __launch_bounds__(256)
void cast_A(const float* __restrict__ A, __bf16* __restrict__ Ab) {
  const int i = blockIdx.x * 256 + threadIdx.x;
  const float4 f = ((const float4*)A)[i];
  bf16x4 o;
  o[0] = (__bf16)f.x; o[1] = (__bf16)f.y; o[2] = (__bf16)f.z; o[3] = (__bf16)f.w;
  ((bf16x4*)Ab)[i] = o;
}

// ---------------- diffusion GEMM (R2-verified structure): D[b][w] = sum_v SRC[b][v] * A_s[w][v] ----------------
__global__ __launch_bounds__(256)
void gemm_bf16(const __bf16* __restrict__ Ab, const __bf16* __restrict__ SRC,
               __bf16* __restrict__ DSTB, size_t srcStride, size_t dstStride) {
  const int tid = threadIdx.x;
  const int lane = tid & 63, wave = tid >> 6, q = lane >> 4;
  const int bx = blockIdx.x, by = blockIdx.y, s = blockIdx.z;

  const __bf16* Amat = Ab + (size_t)s * 512 * 512;
  const __bf16* B = SRC + (size_t)s * srcStride;
  __bf16* D = DSTB + (size_t)s * dstStride;

  const int W0 = by * 128, B0 = bx * 128;
  const int wm = wave >> 1, wn = wave & 1;

  __shared__ __bf16 As[128 * 64];
  __shared__ __bf16 Bs[128 * 64];

  f32x4 acc[4][4];
  #pragma unroll
  for (int m = 0; m < 4; ++m)
    #pragma unroll
    for (int n = 0; n < 4; ++n) acc[m][n] = {0.f, 0.f, 0.f, 0.f};

  const int srow = lane >> 3, spos = lane & 7;

  for (int kt = 0; kt < 8; ++kt) {
    const int k0 = kt * 64;
    #pragma unroll
    for (int i = 0; i < 4; ++i) {
      const int slot = i * 4 + wave;
      const int r = slot * 8 + srow;
      const int gc = spos ^ (r & 7);          // inverse-swizzled global source (rule 21)
      const __bf16* ga = Amat + (size_t)(W0 + r) * 512 + k0 + gc * 8;
      const __bf16* gb = B    + (size_t)(B0 + r) * 512 + k0 + gc * 8;
      char* la = (char*)As + slot * 1024 + lane * 16;
      char* lb = (char*)Bs + slot * 1024 + lane * 16;
      __builtin_amdgcn_global_load_lds((const __attribute__((address_space(1))) unsigned int*)ga,
                                       (__attribute__((address_space(3))) unsigned int*)la, 16, 0, 0);
      __builtin_amdgcn_global_load_lds((const __attribute__((address_space(1))) unsigned int*)gb,
                                       (__attribute__((address_space(3))) unsigned int*)lb, 16, 0, 0);
    }
    __syncthreads();
    #pragma unroll
    for (int ks = 0; ks < 2; ++ks) {
      bf16x8 af[4], df[4];
      const int ch = ks * 4 + q;
      #pragma unroll
      for (int m = 0; m < 4; ++m) {                    // A_s frags: rows = w
        const int r = wm * 64 + m * 16 + (lane & 15);
        af[m] = *(const bf16x8*)((const char*)As + r * 128 + ((ch ^ (r & 7)) << 4));
      }
      #pragma unroll
      for (int n = 0; n < 4; ++n) {                    // data frags: rows = b
        const int r = wn * 64 + n * 16 + (lane & 15);
        df[n] = *(const bf16x8*)((const char*)Bs + r * 128 + ((ch ^ (r & 7)) << 4));
      }
      #pragma unroll
      for (int m = 0; m < 4; ++m)
        #pragma unroll
        for (int n = 0; n < 4; ++n)
          acc[m][n] = __builtin_amdgcn_mfma_f32_16x16x32_bf16(af[m], df[n], acc[m][n], 0, 0, 0);
    }
    __syncthreads();
  }

  // D: col=lane&15 -> b, row=(lane>>4)*4+reg -> w. Store 4 consecutive w (8B) per lane.
  #pragma unroll
  for (int m = 0; m < 4; ++m) {
    const int w = W0 + wm * 64 + m * 16 + q * 4;
    #pragma unroll
    for (int n = 0; n < 4; ++n) {
      const int b = B0 + wn * 64 + n * 16 + (lane & 15);
      bf16x4 o4;
      o4[0] = (__bf16)acc[m][n][0]; o4[1] = (__bf16)acc[m][n][1];
      o4[2] = (__bf16)acc[m][n][2]; o4[3] = (__bf16)acc[m][n][3];
      *(bf16x4*)(D + (size_t)b * 512 + w) = o4;
    }
  }
}

// ---------------- temporal conv as MFMA, transpose via scalar LDS gathers ----------------
// D[v][o] (per t, o-half): acc[t][of] += H[l=t+kt] (rows=v, k=c) * W2 (rows=o, k=c)
__global__ __launch_bounds__(256)
void conv_kernel(const __bf16* __restrict__ Xv2, const __bf16* __restrict__ Y1,
                 const __bf16* __restrict__ Y2, const float* __restrict__ W,
                 const float* __restrict__ bias, float* __restrict__ y) {
  const int vt = blockIdx.x;   // 8 tiles of 64 v
  const int n  = blockIdx.y;
  const int tid = threadIdx.x;
  const int lane = tid & 63, wave = tid >> 6, q = lane >> 4, r16 = lane & 15;

  __shared__ char sm[59392];   // Hs [l(13)][c(32)][v(64)x2B] = 53248 + Ws 6144; Ds overlays Hs
  char* Ws = sm + 53248;

  const __bf16* gsrc[7] = {Xv2, Y1, Y2, Y1 + (size_t)SXE, Y2 + (size_t)SXE,
                           Y1 + 2 * (size_t)SXE, Y2 + 2 * (size_t)SXE};

  f32x4 acc[11][2];
  #pragma unroll
  for (int t = 0; t < 11; ++t) { acc[t][0] = {0,0,0,0}; acc[t][1] = {0,0,0,0}; }

  for (int g = 0; g < 7; ++g) {
    __syncthreads();
    // stage H chunk: 13 l x 32 c rows, 128 B (64 v) each -> Hs[l][c][v] linear
    const __bf16* src = gsrc[g] + ((size_t)n * 416) * 512 + vt * 64;
    #pragma unroll
    for (int it = 0; it < 13; ++it) {
      const int idx = it * 256 + tid;
      const int l = idx >> 8, rem = idx & 255, c = rem >> 3, h = rem & 7;
      i32x4 val = *(const i32x4*)(src + ((size_t)(l * 32 + c) << 9) + h * 8);
      *(i32x4*)(sm + l * 4096 + c * 128 + h * 16) = val;
    }
    // W fragments (R4-verified build): entry idx=f*128+lw*2+half (8B): o=of*16+(lw&15), c=g*32+(lw>>4)*8+half*4+j
    for (int idx = tid; idx < 768; idx += 256) {
      const int f = idx >> 7, rem2 = idx & 127, lw = rem2 >> 1, half = rem2 & 1;
      const int kt = f >> 1, of = f & 1;
      const int o = of * 16 + (lw & 15);
      const int cc = g * 32 + (lw >> 4) * 8 + half * 4;
      bf16x4 w4;
      #pragma unroll
      for (int j = 0; j < 4; ++j)
        w4[j] = (__bf16)W[((size_t)o * 224 + cc + j) * 3 + kt];
      *(bf16x4*)(Ws + idx * 8) = w4;
    }
    __syncthreads();

    // H-frags via scalar gathers: lane (q,r16): v = wave*16+r16, elems j -> c = q*8+j
    bf16x8 a8[13];
    const int gbase = q * 8 * 128 + (wave * 16 + r16) * 2;
    #pragma unroll
    for (int l = 0; l < 13; ++l) {
      bf16x8 a;
      #pragma unroll
      for (int j = 0; j < 8; ++j)
        a[j] = *(const __bf16*)(sm + l * 4096 + gbase + j * 128);
      a8[l] = a;
    }
    // W-frags: lane reads entries 2*lane, 2*lane+1 -> elems j: c = q*8+j, o = of*16+r16 (R4-verified)
    bf16x8 wf[6];
    #pragma unroll
    for (int f = 0; f < 6; ++f)
      wf[f] = *(const bf16x8*)(Ws + (f * 64 + lane) * 16);

    #pragma unroll
    for (int kt = 0; kt < 3; ++kt)
      #pragma unroll
      for (int of = 0; of < 2; ++of)
        #pragma unroll
        for (int t = 0; t < 11; ++t)
          acc[t][of] = __builtin_amdgcn_mfma_f32_16x16x32_bf16(a8[t + kt], wf[kt * 2 + of], acc[t][of], 0, 0, 0);
  }

  // epilogue (R4-verified): D rows = v = wave*16+q*4+reg, cols = o = lane&15 (+16 per pass)
  float* Ds = (float*)sm;
  const int o16 = lane & 15;
  for (int p = 0; p < 2; ++p) {
    __syncthreads();
    #pragma unroll
    for (int t = 0; t < 11; ++t) {
      const int vbase = wave * 16 + q * 4;
      #pragma unroll
      for (int rg = 0; rg < 4; ++rg)
        Ds[o16 * 708 + (vbase + rg) * 11 + t] = acc[t][p][rg];
    }
    __syncthreads();
    for (int i = 0; i < 11; ++i) {
      const int cg = tid + i * 256;           // 16 o x 176 f32x4-chunks
      const int oo = cg / 176, ch = cg - oo * 176;
      f32x4 v4 = *(const f32x4*)(Ds + oo * 708 + ch * 4);
      const float bo = bias[p * 16 + oo];
      v4[0] += bo; v4[1] += bo; v4[2] += bo; v4[3] += bo;
      float* yp = y + (((size_t)n * 32 + p * 16 + oo) * 512 + vt * 64) * 11 + ch * 4;
      *(f32x4*)yp = v4;
    }
  }
}

extern "C" void kernel_launch(void* const* d_in, const int* in_sizes, int n_in,
                              void* d_out, int out_size, void* d_ws, size_t ws_size,
                              hipStream_t stream) {
  (void)in_sizes; (void)n_in; (void)out_size; (void)ws_size;
  const float* x = (const float*)d_in[0];
  const float* A = (const float*)d_in[1];
  const float* W = (const float*)d_in[2];
  const float* b = (const float*)d_in[3];
  float* y = (float*)d_out;

  // ws: Xv2 (27.3 MB) + Y1 x3 (81.8) + Y2 x3 (81.8) + Ab (1.6) = 192.4 MB (== R2 known-good)
  char* ws = (char*)d_ws;
  const size_t SXB = (size_t)SXE * 2;
  __bf16* Xv2 = (__bf16*)ws;
  __bf16* Y1  = (__bf16*)(ws + SXB);
  __bf16* Y2  = (__bf16*)(ws + 4 * SXB);
  __bf16* Ab  = (__bf16*)(ws + 7 * SXB);

  cast_A<<<dim3(768), 256, 0, stream>>>(A, Ab);
  prep_x<<<dim3(32, 64), 256, 0, stream>>>(x, Xv2);
  gemm_bf16<<<dim3(208, 4, 3), 256, 0, stream>>>(Ab, Xv2, Y1, 0, (size_t)SXE);
  gemm_bf16<<<dim3(208, 4, 3), 256, 0, stream>>>(Ab, Y1, Y2, (size_t)SXE, (size_t)SXE);
  conv_kernel<<<dim3(8, 64), 256, 0, stream>>>(Xv2, Y1, Y2, W, b, y);
}